// Round 14
// baseline (360.493 us; speedup 1.0000x reference)
//
#include <hip/hip_runtime.h>
#include <cstdint>
#include <cstddef>

// ---------- types / helpers ----------
typedef __attribute__((ext_vector_type(8))) short bf16x8;           // 8 bf16 = 4 VGPR
typedef __attribute__((ext_vector_type(8))) unsigned short u16x8;   // raw 16B load
typedef __attribute__((ext_vector_type(4))) unsigned short u16x4;   // 8B store
typedef __attribute__((ext_vector_type(4))) unsigned u32x4;         // 16B word group
typedef __attribute__((ext_vector_type(4))) float f32x4;            // MFMA C/D

#define MFMA16(A, B, C) __builtin_amdgcn_mfma_f32_16x16x32_bf16((A), (B), (C), 0, 0, 0)

__device__ __forceinline__ unsigned short f2bf(float f) {
  unsigned u = __builtin_bit_cast(unsigned, f);
  u += 0x7FFFu + ((u >> 16) & 1u);   // RNE
  return (unsigned short)(u >> 16);
}
__device__ __forceinline__ unsigned packbf2(float lo, float hi) {  // 2xbf16 RNE
  unsigned ul = __builtin_bit_cast(unsigned, lo);
  unsigned uh = __builtin_bit_cast(unsigned, hi);
  ul += 0x7FFFu + ((ul >> 16) & 1u);
  uh += 0x7FFFu + ((uh >> 16) & 1u);
  return (ul >> 16) | (uh & 0xffff0000u);
}

// global -> LDS async, 16B/lane. LDS dest wave-uniform (HW adds lane*16).
__device__ __forceinline__ void gload_lds16(const void* gsrc, void* ldst) {
  __builtin_amdgcn_global_load_lds(
      (const __attribute__((address_space(1))) unsigned int*)gsrc,
      (__attribute__((address_space(3))) unsigned int*)ldst,
      16, 0, 0);
}

// ---------- fused f32 -> bf16 down-convert (1 launch for x + 4 weights) ----------
__global__ __launch_bounds__(256) void cvt_all(
    const float* __restrict__ sx, const float* __restrict__ s1,
    const float* __restrict__ s2, const float* __restrict__ s3,
    const float* __restrict__ s4,
    unsigned short* __restrict__ dx, unsigned short* __restrict__ d1,
    unsigned short* __restrict__ d2, unsigned short* __restrict__ d3,
    unsigned short* __restrict__ d4) {
  const int y = blockIdx.y;
  const float* src;
  unsigned short* dst;
  if (y == 0)      { src = sx;               dst = dx; }
  else if (y == 1) { src = sx + (1u << 22);  dst = dx + (1u << 22); }
  else if (y == 2) { src = s1; dst = d1; }
  else if (y == 3) { src = s2; dst = d2; }
  else if (y == 4) { src = s3; dst = d3; }
  else             { src = s4; dst = d4; }
  const size_t i = ((size_t)blockIdx.x * 256 + threadIdx.x) * 4;
  f32x4 v = *(const f32x4*)(src + i);
  u16x4 o;
  o[0] = f2bf(v[0]); o[1] = f2bf(v[1]); o[2] = f2bf(v[2]); o[3] = f2bf(v[3]);
  *(u16x4*)(dst + i) = o;
}

// ---------- counted-vmcnt GEMM, 1 barrier per K-tile (r13-proven) ----------
// BM=256, BN=128, BK=64; 8 waves (4M x 2N), per-wave 64x64 (acc[4][4]).
// Triple-buffered LDS (144KB): stage kt+2 while computing kt; vmcnt(6) at the
// single end-of-tile barrier (T4: never 0 mid-loop).
// T2 XOR-swizzle (elem ^= (row&7)<<3) on gload SOURCE + ds_read (rule #21).
// MODE 0: C row-major f32. MODE 1: QKV head-permute bf16, LDS-staged coalesced.
template <int MODE>
__device__ __forceinline__ void gemm8_tile(const unsigned short* __restrict__ A,
                                           const unsigned short* __restrict__ W,
                                           const float* __restrict__ bias,
                                           void* __restrict__ C,
                                           int bx, int by) {
  constexpr int K = 2048, N = 2048;
  constexpr int NT = K / 64;                  // 32 K-tiles
  __shared__ __align__(16) unsigned short lA[3][256 * 64];  // 96KB
  __shared__ __align__(16) unsigned short lB[3][128 * 64];  // 48KB
  const int tid = threadIdx.x;
  const int lane = tid & 63;
  const int w = tid >> 6;                     // 0..7
  const int g = lane >> 4;
  const int l15 = lane & 15;
  const int wm = w >> 1, wn = w & 1;
  const int m0 = by * 256, n0 = bx * 128;

  auto stageA = [&](int kt, int buf) {        // 4 gloads: 256x64 = 2048 slots
    const int kb = kt * 64;
#pragma unroll
    for (int it = 0; it < 4; ++it) {
      const int f = it * 512 + tid;
      const int r = f >> 3, s = f & 7;
      gload_lds16(A + (size_t)(m0 + r) * K + kb + ((s * 8) ^ ((r & 7) << 3)),
                  (char*)&lA[buf][0] + (it * 512 + w * 64) * 16);
    }
  };
  auto stageB = [&](int kt, int buf) {        // 2 gloads: 128x64 = 1024 slots
    const int kb = kt * 64;
#pragma unroll
    for (int it = 0; it < 2; ++it) {
      const int f = it * 512 + tid;
      const int r = f >> 3, s = f & 7;
      gload_lds16(W + (size_t)(n0 + r) * K + kb + ((s * 8) ^ ((r & 7) << 3)),
                  (char*)&lB[buf][0] + (it * 512 + w * 64) * 16);
    }
  };

  f32x4 acc[4][4];
#pragma unroll
  for (int i = 0; i < 4; ++i)
#pragma unroll
    for (int j = 0; j < 4; ++j) acc[i][j] = f32x4{0.f, 0.f, 0.f, 0.f};

  // ---- prologue: tiles 0,1 -> bufs 0,1; wait tile0 (6 of 12 retire)
  stageA(0, 0); stageB(0, 0);
  stageA(1, 1); stageB(1, 1);
  asm volatile("s_waitcnt vmcnt(6)" ::: "memory");
  __builtin_amdgcn_s_barrier();
  __builtin_amdgcn_sched_barrier(0);

  int cur = 0, nxt = 2;
  for (int kt = 0; kt < NT; ++kt) {
    const unsigned short* As = &lA[cur][0];
    const unsigned short* Bs = &lB[cur][0];
    bf16x8 bfr[4][2], af[4][2];
#pragma unroll
    for (int ni = 0; ni < 4; ++ni) {
      const int rb = wn * 64 + ni * 16 + l15;
#pragma unroll
      for (int kh = 0; kh < 2; ++kh)
        bfr[ni][kh] =
            *(const bf16x8*)&Bs[rb * 64 + ((kh * 32 + g * 8) ^ ((rb & 7) << 3))];
    }
#pragma unroll
    for (int mi = 0; mi < 4; ++mi) {
      const int ra = wm * 64 + mi * 16 + l15;
#pragma unroll
      for (int kh = 0; kh < 2; ++kh)
        af[mi][kh] =
            *(const bf16x8*)&As[ra * 64 + ((kh * 32 + g * 8) ^ ((ra & 7) << 3))];
    }
    if (kt + 2 < NT) { stageA(kt + 2, nxt); stageB(kt + 2, nxt); }
    __builtin_amdgcn_s_setprio(1);
#pragma unroll
    for (int kh = 0; kh < 2; ++kh)
#pragma unroll
      for (int mi = 0; mi < 4; ++mi)
#pragma unroll
        for (int ni = 0; ni < 4; ++ni)
          acc[mi][ni] = MFMA16(af[mi][kh], bfr[ni][kh], acc[mi][ni]);
    __builtin_amdgcn_s_setprio(0);
    // single end-of-tile sync: tile kt+1 resident, kt+2's 6 loads in flight.
    if (kt < NT - 2)       asm volatile("s_waitcnt vmcnt(6)" ::: "memory");
    else if (kt == NT - 2) asm volatile("s_waitcnt vmcnt(0)" ::: "memory");
    __builtin_amdgcn_s_barrier();
    __builtin_amdgcn_sched_barrier(0);
    cur = (cur == 2) ? 0 : cur + 1;
    nxt = (nxt == 2) ? 0 : nxt + 1;
  }

  // ---- epilogue: D layout col=lane&15 (n), row=4g+rr (m)
  if (MODE == 0) {
#pragma unroll
    for (int ni = 0; ni < 4; ++ni) {
      const int n = n0 + wn * 64 + ni * 16 + l15;
      const float bval = bias[n];
#pragma unroll
      for (int mi = 0; mi < 4; ++mi) {
        const int mb = m0 + wm * 64 + mi * 16 + g * 4;
#pragma unroll
        for (int r = 0; r < 4; ++r)
          ((float*)C)[(size_t)(mb + r) * N + n] = acc[mi][ni][r] + bval;
      }
    }
  } else {
    // stage 256x128 bf16 C-tile in dead lA (64KB), then coalesced b128 stores
    unsigned short* lc = &lA[0][0];
#pragma unroll
    for (int ni = 0; ni < 4; ++ni) {
      const int n = n0 + wn * 64 + ni * 16 + l15;
      const float bval = bias[n];
      const int col = wn * 64 + ni * 16 + l15;
#pragma unroll
      for (int mi = 0; mi < 4; ++mi) {
        const int rbase = wm * 64 + mi * 16 + g * 4;
#pragma unroll
        for (int r = 0; r < 4; ++r)
          lc[(rbase + r) * 128 + col] = f2bf(acc[mi][ni][r] + bval);
      }
    }
    __syncthreads();
    const int bb = m0 >> 11;                   // constant per block
    const int hh = n0 >> 7;                    // constant per block
    unsigned short* dst = (unsigned short*)C +
        (((size_t)(bb * 16 + hh) * 2048) + (m0 & 2047)) * 128;
#pragma unroll
    for (int p = 0; p < 8; ++p) {
      const int f = p * 512 + tid;             // 4096 slots of 8 u16
      const int row = f >> 4, slot = f & 15;
      *(u16x8*)(dst + (size_t)row * 128 + slot * 8) =
          *(const u16x8*)&lc[row * 128 + slot * 8];
    }
  }
}

// T1 XCD-aware bijective remap: blocks resident on one XCD (o%8 const) cover a
// compact by-major tile range -> A-panels L2-local, working set L3-local.
__global__ __launch_bounds__(512, 2) void gemm_qkv(
    const unsigned short* __restrict__ x,
    const unsigned short* __restrict__ wq, const float* __restrict__ bq,
    const unsigned short* __restrict__ wk, const float* __restrict__ bk,
    const unsigned short* __restrict__ wv, const float* __restrict__ bv,
    unsigned short* __restrict__ qo, unsigned short* __restrict__ ko,
    unsigned short* __restrict__ vo) {
  const int o = blockIdx.x + ((int)blockIdx.y << 4) + ((int)blockIdx.z << 8);
  const int t = (o & 7) * 96 + (o >> 3);      // 768 = 8 x 96, bijective
  const int z = t >> 8;
  const int by = (t & 255) >> 4;
  const int bx = t & 15;
  const unsigned short* W = (z == 0) ? wq : (z == 1) ? wk : wv;
  const float* B = (z == 0) ? bq : (z == 1) ? bk : bv;
  unsigned short* O = (z == 0) ? qo : (z == 1) ? ko : vo;
  gemm8_tile<1>(x, W, B, O, bx, by);
}

__global__ __launch_bounds__(512, 2) void gemm_out(
    const unsigned short* __restrict__ A, const unsigned short* __restrict__ wo,
    const float* __restrict__ bo, float* __restrict__ C) {
  const int o = blockIdx.x + ((int)blockIdx.y << 4);
  const int t = (o & 7) * 32 + (o >> 3);      // 256 = 8 x 32, bijective
  const int by = t >> 4;
  const int bx = t & 15;
  gemm8_tile<0>(A, wo, bo, C, bx, by);
}

// ---------- causal flash attention, swapped-QK^T, in-register P ----------
// lP ELIMINATED: P redistribution for the PV A-frag is done with 32 __shfl +
// cndmask (dest (g,l15) word w of half h = packbf2 word held by lane
// (g'=(2g+(w>>1))&3, l15) at jb=2h+(g>>1); verified per-index). LDS drops
// 69.6KB -> 51.2KB -> 3 blocks/CU (the r11 bound failed only because lP
// blocked 3 blocks; VGPR ~120 < 170 cap).
__global__ __launch_bounds__(256, 3) void attn_fwd(
    const unsigned short* __restrict__ Q, const unsigned short* __restrict__ K,
    const unsigned short* __restrict__ V, unsigned short* __restrict__ O) {
  __shared__ unsigned short lK[2][64 * 128];  // 32KB dbuf (swizzled slots)
  __shared__ unsigned short lV[128 * 72];     // V^T [d][j], 144B rows
  const int tid = threadIdx.x;
  const int lane = tid & 63;
  const int w = tid >> 6;
  const int g = lane >> 4;
  const int l15 = lane & 15;
  const int bx = blockIdx.x;
  const int bh = blockIdx.y;
  const int qb = (bh >= 16) ? (15 - bx) : bx;  // CU-pair balance
  const int nt = 2 * qb + 2;
  const size_t head_off = (size_t)bh * 2048 * 128;
  const unsigned short* Qh = Q + head_off;
  const unsigned short* Kh = K + head_off;
  const unsigned short* Vh = V + head_off;

  bf16x8 qf[2][4];
#pragma unroll
  for (int mi = 0; mi < 2; ++mi) {
    const int row = qb * 128 + w * 32 + mi * 16 + l15;
#pragma unroll
    for (int ks = 0; ks < 4; ++ks) {
      const int s = ks * 4 + g;
      qf[mi][ks] = *(const bf16x8*)(Qh + (size_t)row * 128 + s * 8);
    }
  }

  const int vj0 = (tid & 31) * 2;
  const int vd0 = (tid >> 5) * 16;
  u16x8 vr[4];

  auto stageK = [&](int t, int buf) {
#pragma unroll
    for (int it = 0; it < 4; ++it) {
      const int f = it * 256 + tid;
      const int r = f >> 4, s = f & 15;
      const int sc = s ^ (r & 7);
      gload_lds16(Kh + (size_t)(t * 64 + r) * 128 + sc * 8,
                  (char*)&lK[buf][0] + (it * 256 + w * 64) * 16);
    }
  };
  auto loadV = [&](int t) {
    const unsigned short* vp = Vh + (size_t)(t * 64 + vj0) * 128 + vd0;
    vr[0] = *(const u16x8*)(vp);
    vr[1] = *(const u16x8*)(vp + 8);
    vr[2] = *(const u16x8*)(vp + 128);
    vr[3] = *(const u16x8*)(vp + 136);
  };
  auto writeV = [&]() {
#pragma unroll
    for (int dd = 0; dd < 8; ++dd) {
      unsigned pk0 = (unsigned)vr[0][dd] | ((unsigned)vr[2][dd] << 16);
      unsigned pk1 = (unsigned)vr[1][dd] | ((unsigned)vr[3][dd] << 16);
      *(unsigned*)&lV[(vd0 + dd) * 72 + vj0] = pk0;
      *(unsigned*)&lV[(vd0 + 8 + dd) * 72 + vj0] = pk1;
    }
  };

  loadV(0);
  stageK(0, 0);
  writeV();
  __syncthreads();

  f32x4 acc_o[2][8];
#pragma unroll
  for (int mi = 0; mi < 2; ++mi)
#pragma unroll
    for (int i = 0; i < 8; ++i) acc_o[mi][i] = f32x4{0.f, 0.f, 0.f, 0.f};
  float mrun[2], lrun[2];
#pragma unroll
  for (int mi = 0; mi < 2; ++mi) { mrun[mi] = -__builtin_inff(); lrun[mi] = 0.f; }

  const float SL2E = 0.12751744f;
  const int qrow0 = qb * 128 + w * 32;
  const int srcA = l15 + 16 * ((2 * g) & 3);      // shfl sources (same l15)
  const int srcB = l15 + 16 * ((2 * g + 1) & 3);
  const bool ghi = (g & 2) != 0;                  // g>>1 selects jb parity

  int cur = 0;
  for (int t = 0; t < nt; ++t) {
    const int kv0 = t * 64;
    const bool pre = (t + 1 < nt);
    if (pre) { loadV(t + 1); stageK(t + 1, cur ^ 1); }

    const bool active = (kv0 <= qrow0 + 31);
    if (active) {
      const unsigned short* lKc = &lK[cur][0];
      f32x4 sacc[4][2];
#pragma unroll
      for (int jb = 0; jb < 4; ++jb) {
        sacc[jb][0] = f32x4{0.f, 0.f, 0.f, 0.f};
        sacc[jb][1] = f32x4{0.f, 0.f, 0.f, 0.f};
      }
      __builtin_amdgcn_s_setprio(1);
#pragma unroll
      for (int jb = 0; jb < 4; ++jb) {
        const int r = jb * 16 + l15;
#pragma unroll
        for (int ks = 0; ks < 4; ++ks) {
          const int s = ks * 4 + g;
          bf16x8 kf = *(const bf16x8*)&lKc[r * 128 + (s ^ (r & 7)) * 8];
          sacc[jb][0] = MFMA16(kf, qf[0][ks], sacc[jb][0]);
          sacc[jb][1] = MFMA16(kf, qf[1][ks], sacc[jb][1]);
        }
      }
      __builtin_amdgcn_s_setprio(0);

      const bool need_mask = (kv0 + 63 >= qrow0);
      float psc_l[2];
      bool defer_mi[2];
      unsigned pws[2][4][2];                  // packed P words (static idx only)
#pragma unroll
      for (int mi = 0; mi < 2; ++mi) {
        const int icol = qrow0 + mi * 16 + l15;
        f32x4 pe[4];
#pragma unroll
        for (int jb = 0; jb < 4; ++jb) {
#pragma unroll
          for (int rr = 0; rr < 4; ++rr) {
            float tv = sacc[jb][mi][rr] * SL2E;
            if (need_mask && (kv0 + jb * 16 + g * 4 + rr > icol))
              tv = -__builtin_inff();
            pe[jb][rr] = tv;
          }
        }
        f32x4 m4 = f32x4{fmaxf(fmaxf(pe[0][0], pe[1][0]), fmaxf(pe[2][0], pe[3][0])),
                         fmaxf(fmaxf(pe[0][1], pe[1][1]), fmaxf(pe[2][1], pe[3][1])),
                         fmaxf(fmaxf(pe[0][2], pe[1][2]), fmaxf(pe[2][2], pe[3][2])),
                         fmaxf(fmaxf(pe[0][3], pe[1][3]), fmaxf(pe[2][3], pe[3][3]))};
        float mx = fmaxf(fmaxf(m4[0], m4[1]), fmaxf(m4[2], m4[3]));
        mx = fmaxf(mx, __shfl_xor(mx, 16));
        mx = fmaxf(mx, __shfl_xor(mx, 32));
        // T13: defer the max update when growth <= 8 (wave-uniform)
        const bool dfr = (__all(mx - mrun[mi] <= 8.0f) != 0);
        defer_mi[mi] = dfr;
        if (dfr) {
          psc_l[mi] = 1.0f;
        } else {
          const float mnew = fmaxf(mrun[mi], mx);
          psc_l[mi] = exp2f(mrun[mi] - mnew);
          mrun[mi] = mnew;
        }
        float rs = 0.f;
#pragma unroll
        for (int jb = 0; jb < 4; ++jb) {
#pragma unroll
          for (int rr = 0; rr < 4; ++rr) {
            const float e = exp2f(pe[jb][rr] - mrun[mi]);  // <= 2^8 if deferred
            pe[jb][rr] = e;
            rs += e;
          }
        }
        rs += __shfl_xor(rs, 16);
        rs += __shfl_xor(rs, 32);
        lrun[mi] = lrun[mi] * psc_l[mi] + rs;
#pragma unroll
        for (int jb = 0; jb < 4; ++jb) {
          pws[mi][jb][0] = packbf2(pe[jb][0], pe[jb][1]);
          pws[mi][jb][1] = packbf2(pe[jb][2], pe[jb][3]);
        }
      }

      // rescale acc_o only when not deferred (wave-uniform branch per mi)
#pragma unroll
      for (int mi = 0; mi < 2; ++mi) {
        if (!defer_mi[mi]) {
          float psc_pv[4];
#pragma unroll
          for (int r = 0; r < 4; ++r)
            psc_pv[r] = __shfl(psc_l[mi], g * 4 + r);
#pragma unroll
          for (int nb = 0; nb < 8; ++nb)
#pragma unroll
            for (int r = 0; r < 4; ++r) acc_o[mi][nb][r] *= psc_pv[r];
        }
      }

      // ---- build PV A-frags in-register: dest word w (j=32h+8g+2w,+1) comes
      // from lane srcA (w<2) / srcB (w>=2), jb=2h+(g>>1) -> shfl both jb
      // candidates, select by ghi.
      bf16x8 pa[2][2];
#pragma unroll
      for (int mi = 0; mi < 2; ++mi) {
#pragma unroll
        for (int h = 0; h < 2; ++h) {
          const unsigned a0 = __shfl(pws[mi][2 * h][0], srcA);
          const unsigned a1 = __shfl(pws[mi][2 * h][1], srcA);
          const unsigned a2 = __shfl(pws[mi][2 * h][0], srcB);
          const unsigned a3 = __shfl(pws[mi][2 * h][1], srcB);
          const unsigned b0 = __shfl(pws[mi][2 * h + 1][0], srcA);
          const unsigned b1 = __shfl(pws[mi][2 * h + 1][1], srcA);
          const unsigned b2 = __shfl(pws[mi][2 * h + 1][0], srcB);
          const unsigned b3 = __shfl(pws[mi][2 * h + 1][1], srcB);
          u32x4 wv;
          wv[0] = ghi ? b0 : a0;
          wv[1] = ghi ? b1 : a1;
          wv[2] = ghi ? b2 : a2;
          wv[3] = ghi ? b3 : a3;
          pa[mi][h] = __builtin_bit_cast(bf16x8, wv);
        }
      }

      __builtin_amdgcn_s_setprio(1);
#pragma unroll
      for (int nb = 0; nb < 8; ++nb) {
        const int vrow = nb * 16 + l15;
#pragma unroll
        for (int h = 0; h < 2; ++h) {
          bf16x8 vf = *(const bf16x8*)&lV[vrow * 72 + h * 32 + g * 8];
          acc_o[0][nb] = MFMA16(pa[0][h], vf, acc_o[0][nb]);
          acc_o[1][nb] = MFMA16(pa[1][h], vf, acc_o[1][nb]);
        }
      }
      __builtin_amdgcn_s_setprio(0);
    }

    __syncthreads();
    if (pre) writeV();
    __syncthreads();
    cur ^= 1;
  }

  const int b = bh >> 4, hh = bh & 15;
  float linv[2][4];
#pragma unroll
  for (int mi = 0; mi < 2; ++mi)
#pragma unroll
    for (int r = 0; r < 4; ++r)
      linv[mi][r] = 1.0f / __shfl(lrun[mi], g * 4 + r);
#pragma unroll
  for (int mi = 0; mi < 2; ++mi)
#pragma unroll
    for (int nb = 0; nb < 8; ++nb)
#pragma unroll
      for (int r = 0; r < 4; ++r) {
        const int i = qb * 128 + w * 32 + mi * 16 + g * 4 + r;
        const float o = acc_o[mi][nb][r] * linv[mi][r];
        O[((size_t)(b * 2048 + i)) * 2048 + hh * 128 + nb * 16 + l15] = f2bf(o);
      }
}

// ---------- launch ----------
extern "C" void kernel_launch(void* const* d_in, const int* in_sizes, int n_in,
                              void* d_out, int out_size, void* d_ws, size_t ws_size,
                              hipStream_t stream) {
  const float* x  = (const float*)d_in[0];
  const float* wq = (const float*)d_in[1];
  const float* bq = (const float*)d_in[2];
  const float* wk = (const float*)d_in[3];
  const float* bk = (const float*)d_in[4];
  const float* wv = (const float*)d_in[5];
  const float* bv = (const float*)d_in[6];
  const float* wo = (const float*)d_in[7];
  const float* bo = (const float*)d_in[8];

  const size_t NX = (size_t)2 * 2048 * 2048;
  const size_t NW = (size_t)2048 * 2048;
  const size_t need = (NX + 4 * NW + 3 * NX) * sizeof(unsigned short);  // 96 MB
  if (ws_size < need) return;
  unsigned short* xbf  = (unsigned short*)d_ws;
  unsigned short* wqb  = xbf + NX;
  unsigned short* wkb  = wqb + NW;
  unsigned short* wvb  = wkb + NW;
  unsigned short* wob  = wvb + NW;
  unsigned short* qbuf = wob + NW;
  unsigned short* kbuf = qbuf + NX;
  unsigned short* vbuf = kbuf + NX;
  unsigned short* aobuf = xbf;  // x dead after gemm_qkv (stream-ordered)

  cvt_all<<<dim3(4096, 6), 256, 0, stream>>>(x, wq, wk, wv, wo,
                                             xbf, wqb, wkb, wvb, wob);
  gemm_qkv<<<dim3(16, 16, 3), 512, 0, stream>>>(xbf, wqb, bq, wkb, bk, wvb, bv,
                                                qbuf, kbuf, vbuf);
  attn_fwd<<<dim3(16, 32), 256, 0, stream>>>(qbuf, kbuf, vbuf, aobuf);
  gemm_out<<<dim3(16, 16), 512, 0, stream>>>(aobuf, wob, bo, (float*)d_out);
}

// Round 15
// 276.725 us; speedup vs baseline: 1.3027x; 1.3027x over previous
//
#include <hip/hip_runtime.h>
#include <cstdint>
#include <cstddef>

// ---------- types / helpers ----------
typedef __attribute__((ext_vector_type(8))) short bf16x8;           // 8 bf16 = 4 VGPR
typedef __attribute__((ext_vector_type(8))) unsigned short u16x8;   // raw 16B load
typedef __attribute__((ext_vector_type(4))) unsigned short u16x4;   // 8B store
typedef __attribute__((ext_vector_type(4))) unsigned u32x4;         // 16B word group
typedef __attribute__((ext_vector_type(4))) float f32x4;            // MFMA C/D

#define MFMA16(A, B, C) __builtin_amdgcn_mfma_f32_16x16x32_bf16((A), (B), (C), 0, 0, 0)

__device__ __forceinline__ unsigned short f2bf(float f) {
  unsigned u = __builtin_bit_cast(unsigned, f);
  u += 0x7FFFu + ((u >> 16) & 1u);   // RNE
  return (unsigned short)(u >> 16);
}
__device__ __forceinline__ unsigned packbf2(float lo, float hi) {  // 2xbf16 RNE
  unsigned ul = __builtin_bit_cast(unsigned, lo);
  unsigned uh = __builtin_bit_cast(unsigned, hi);
  ul += 0x7FFFu + ((ul >> 16) & 1u);
  uh += 0x7FFFu + ((uh >> 16) & 1u);
  return (ul >> 16) | (uh & 0xffff0000u);
}

// global -> LDS async, 16B/lane. LDS dest wave-uniform (HW adds lane*16).
__device__ __forceinline__ void gload_lds16(const void* gsrc, void* ldst) {
  __builtin_amdgcn_global_load_lds(
      (const __attribute__((address_space(1))) unsigned int*)gsrc,
      (__attribute__((address_space(3))) unsigned int*)ldst,
      16, 0, 0);
}

// ---------- fused f32 -> bf16 down-convert (1 launch for x + 4 weights) ----------
__global__ __launch_bounds__(256) void cvt_all(
    const float* __restrict__ sx, const float* __restrict__ s1,
    const float* __restrict__ s2, const float* __restrict__ s3,
    const float* __restrict__ s4,
    unsigned short* __restrict__ dx, unsigned short* __restrict__ d1,
    unsigned short* __restrict__ d2, unsigned short* __restrict__ d3,
    unsigned short* __restrict__ d4) {
  const int y = blockIdx.y;
  const float* src;
  unsigned short* dst;
  if (y == 0)      { src = sx;               dst = dx; }
  else if (y == 1) { src = sx + (1u << 22);  dst = dx + (1u << 22); }
  else if (y == 2) { src = s1; dst = d1; }
  else if (y == 3) { src = s2; dst = d2; }
  else if (y == 4) { src = s3; dst = d3; }
  else             { src = s4; dst = d4; }
  const size_t i = ((size_t)blockIdx.x * 256 + threadIdx.x) * 4;
  f32x4 v = *(const f32x4*)(src + i);
  u16x4 o;
  o[0] = f2bf(v[0]); o[1] = f2bf(v[1]); o[2] = f2bf(v[2]); o[3] = f2bf(v[3]);
  *(u16x4*)(dst + i) = o;
}

// ---------- counted-vmcnt GEMM, 1 barrier per K-tile (r13-proven) ----------
// BM=256, BN=128, BK=64; 8 waves (4M x 2N), per-wave 64x64 (acc[4][4]).
// Triple-buffered LDS (144KB): stage kt+2 while computing kt; vmcnt(6) at the
// single end-of-tile barrier (T4: never 0 mid-loop).
// T2 XOR-swizzle (elem ^= (row&7)<<3) on gload SOURCE + ds_read (rule #21).
// MODE 0: C row-major f32. MODE 1: QKV head-permute bf16, LDS-staged coalesced.
template <int MODE>
__device__ __forceinline__ void gemm8_tile(const unsigned short* __restrict__ A,
                                           const unsigned short* __restrict__ W,
                                           const float* __restrict__ bias,
                                           void* __restrict__ C,
                                           int bx, int by) {
  constexpr int K = 2048, N = 2048;
  constexpr int NT = K / 64;                  // 32 K-tiles
  __shared__ __align__(16) unsigned short lA[3][256 * 64];  // 96KB
  __shared__ __align__(16) unsigned short lB[3][128 * 64];  // 48KB
  const int tid = threadIdx.x;
  const int lane = tid & 63;
  const int w = tid >> 6;                     // 0..7
  const int g = lane >> 4;
  const int l15 = lane & 15;
  const int wm = w >> 1, wn = w & 1;
  const int m0 = by * 256, n0 = bx * 128;

  auto stageA = [&](int kt, int buf) {        // 4 gloads: 256x64 = 2048 slots
    const int kb = kt * 64;
#pragma unroll
    for (int it = 0; it < 4; ++it) {
      const int f = it * 512 + tid;
      const int r = f >> 3, s = f & 7;
      gload_lds16(A + (size_t)(m0 + r) * K + kb + ((s * 8) ^ ((r & 7) << 3)),
                  (char*)&lA[buf][0] + (it * 512 + w * 64) * 16);
    }
  };
  auto stageB = [&](int kt, int buf) {        // 2 gloads: 128x64 = 1024 slots
    const int kb = kt * 64;
#pragma unroll
    for (int it = 0; it < 2; ++it) {
      const int f = it * 512 + tid;
      const int r = f >> 3, s = f & 7;
      gload_lds16(W + (size_t)(n0 + r) * K + kb + ((s * 8) ^ ((r & 7) << 3)),
                  (char*)&lB[buf][0] + (it * 512 + w * 64) * 16);
    }
  };

  f32x4 acc[4][4];
#pragma unroll
  for (int i = 0; i < 4; ++i)
#pragma unroll
    for (int j = 0; j < 4; ++j) acc[i][j] = f32x4{0.f, 0.f, 0.f, 0.f};

  // ---- prologue: tiles 0,1 -> bufs 0,1; wait tile0 (6 of 12 retire)
  stageA(0, 0); stageB(0, 0);
  stageA(1, 1); stageB(1, 1);
  asm volatile("s_waitcnt vmcnt(6)" ::: "memory");
  __builtin_amdgcn_s_barrier();
  __builtin_amdgcn_sched_barrier(0);

  int cur = 0, nxt = 2;
  for (int kt = 0; kt < NT; ++kt) {
    const unsigned short* As = &lA[cur][0];
    const unsigned short* Bs = &lB[cur][0];
    bf16x8 bfr[4][2], af[4][2];
#pragma unroll
    for (int ni = 0; ni < 4; ++ni) {
      const int rb = wn * 64 + ni * 16 + l15;
#pragma unroll
      for (int kh = 0; kh < 2; ++kh)
        bfr[ni][kh] =
            *(const bf16x8*)&Bs[rb * 64 + ((kh * 32 + g * 8) ^ ((rb & 7) << 3))];
    }
#pragma unroll
    for (int mi = 0; mi < 4; ++mi) {
      const int ra = wm * 64 + mi * 16 + l15;
#pragma unroll
      for (int kh = 0; kh < 2; ++kh)
        af[mi][kh] =
            *(const bf16x8*)&As[ra * 64 + ((kh * 32 + g * 8) ^ ((ra & 7) << 3))];
    }
    if (kt + 2 < NT) { stageA(kt + 2, nxt); stageB(kt + 2, nxt); }
    __builtin_amdgcn_s_setprio(1);
#pragma unroll
    for (int kh = 0; kh < 2; ++kh)
#pragma unroll
      for (int mi = 0; mi < 4; ++mi)
#pragma unroll
        for (int ni = 0; ni < 4; ++ni)
          acc[mi][ni] = MFMA16(af[mi][kh], bfr[ni][kh], acc[mi][ni]);
    __builtin_amdgcn_s_setprio(0);
    // single end-of-tile sync: tile kt+1 resident, kt+2's 6 loads in flight.
    if (kt < NT - 2)       asm volatile("s_waitcnt vmcnt(6)" ::: "memory");
    else if (kt == NT - 2) asm volatile("s_waitcnt vmcnt(0)" ::: "memory");
    __builtin_amdgcn_s_barrier();
    __builtin_amdgcn_sched_barrier(0);
    cur = (cur == 2) ? 0 : cur + 1;
    nxt = (nxt == 2) ? 0 : nxt + 1;
  }

  // ---- epilogue: D layout col=lane&15 (n), row=4g+rr (m)
  if (MODE == 0) {
#pragma unroll
    for (int ni = 0; ni < 4; ++ni) {
      const int n = n0 + wn * 64 + ni * 16 + l15;
      const float bval = bias[n];
#pragma unroll
      for (int mi = 0; mi < 4; ++mi) {
        const int mb = m0 + wm * 64 + mi * 16 + g * 4;
#pragma unroll
        for (int r = 0; r < 4; ++r)
          ((float*)C)[(size_t)(mb + r) * N + n] = acc[mi][ni][r] + bval;
      }
    }
  } else {
    // stage 256x128 bf16 C-tile in dead lA (64KB), then coalesced b128 stores
    unsigned short* lc = &lA[0][0];
#pragma unroll
    for (int ni = 0; ni < 4; ++ni) {
      const int n = n0 + wn * 64 + ni * 16 + l15;
      const float bval = bias[n];
      const int col = wn * 64 + ni * 16 + l15;
#pragma unroll
      for (int mi = 0; mi < 4; ++mi) {
        const int rbase = wm * 64 + mi * 16 + g * 4;
#pragma unroll
        for (int r = 0; r < 4; ++r)
          lc[(rbase + r) * 128 + col] = f2bf(acc[mi][ni][r] + bval);
      }
    }
    __syncthreads();
    const int bb = m0 >> 11;                   // constant per block
    const int hh = n0 >> 7;                    // constant per block
    unsigned short* dst = (unsigned short*)C +
        (((size_t)(bb * 16 + hh) * 2048) + (m0 & 2047)) * 128;
#pragma unroll
    for (int p = 0; p < 8; ++p) {
      const int f = p * 512 + tid;             // 4096 slots of 8 u16
      const int row = f >> 4, slot = f & 15;
      *(u16x8*)(dst + (size_t)row * 128 + slot * 8) =
          *(const u16x8*)&lc[row * 128 + slot * 8];
    }
  }
}

// T1 XCD-aware bijective remap: blocks resident on one XCD (o%8 const) cover a
// compact by-major tile range -> A-panels L2-local, working set L3-local.
__global__ __launch_bounds__(512, 2) void gemm_qkv(
    const unsigned short* __restrict__ x,
    const unsigned short* __restrict__ wq, const float* __restrict__ bq,
    const unsigned short* __restrict__ wk, const float* __restrict__ bk,
    const unsigned short* __restrict__ wv, const float* __restrict__ bv,
    unsigned short* __restrict__ qo, unsigned short* __restrict__ ko,
    unsigned short* __restrict__ vo) {
  const int o = blockIdx.x + ((int)blockIdx.y << 4) + ((int)blockIdx.z << 8);
  const int t = (o & 7) * 96 + (o >> 3);      // 768 = 8 x 96, bijective
  const int z = t >> 8;
  const int by = (t & 255) >> 4;
  const int bx = t & 15;
  const unsigned short* W = (z == 0) ? wq : (z == 1) ? wk : wv;
  const float* B = (z == 0) ? bq : (z == 1) ? bk : bv;
  unsigned short* O = (z == 0) ? qo : (z == 1) ? ko : vo;
  gemm8_tile<1>(x, W, B, O, bx, by);
}

__global__ __launch_bounds__(512, 2) void gemm_out(
    const unsigned short* __restrict__ A, const unsigned short* __restrict__ wo,
    const float* __restrict__ bo, float* __restrict__ C) {
  const int o = blockIdx.x + ((int)blockIdx.y << 4);
  const int t = (o & 7) * 32 + (o >> 3);      // 256 = 8 x 32, bijective
  const int by = t >> 4;
  const int bx = t & 15;
  gemm8_tile<0>(A, wo, bo, C, bx, by);
}

// ---------- causal flash attention, swapped-QK^T, in-register P ----------
// lP eliminated (P redistribution via 32 __shfl + cndmask, r14-verified
// numerics). LDS 51.2KB allows 3 blocks/CU by residency. Bound is (256,2):
// r14's (256,3) made the allocator spill ~75MB/dispatch to scratch (VGPR 84,
// WRITE_SIZE 91MB). (256,2) gives a 256-VGPR budget -> no spill; if the
// allocator lands <=168 VGPR the HW still co-schedules 3 blocks/CU.
__global__ __launch_bounds__(256, 2) void attn_fwd(
    const unsigned short* __restrict__ Q, const unsigned short* __restrict__ K,
    const unsigned short* __restrict__ V, unsigned short* __restrict__ O) {
  __shared__ unsigned short lK[2][64 * 128];  // 32KB dbuf (swizzled slots)
  __shared__ unsigned short lV[128 * 72];     // V^T [d][j], 144B rows
  const int tid = threadIdx.x;
  const int lane = tid & 63;
  const int w = tid >> 6;
  const int g = lane >> 4;
  const int l15 = lane & 15;
  const int bx = blockIdx.x;
  const int bh = blockIdx.y;
  const int qb = (bh >= 16) ? (15 - bx) : bx;  // CU-pair balance
  const int nt = 2 * qb + 2;
  const size_t head_off = (size_t)bh * 2048 * 128;
  const unsigned short* Qh = Q + head_off;
  const unsigned short* Kh = K + head_off;
  const unsigned short* Vh = V + head_off;

  bf16x8 qf[2][4];
#pragma unroll
  for (int mi = 0; mi < 2; ++mi) {
    const int row = qb * 128 + w * 32 + mi * 16 + l15;
#pragma unroll
    for (int ks = 0; ks < 4; ++ks) {
      const int s = ks * 4 + g;
      qf[mi][ks] = *(const bf16x8*)(Qh + (size_t)row * 128 + s * 8);
    }
  }

  const int vj0 = (tid & 31) * 2;
  const int vd0 = (tid >> 5) * 16;
  u16x8 vr[4];

  auto stageK = [&](int t, int buf) {
#pragma unroll
    for (int it = 0; it < 4; ++it) {
      const int f = it * 256 + tid;
      const int r = f >> 4, s = f & 15;
      const int sc = s ^ (r & 7);
      gload_lds16(Kh + (size_t)(t * 64 + r) * 128 + sc * 8,
                  (char*)&lK[buf][0] + (it * 256 + w * 64) * 16);
    }
  };
  auto loadV = [&](int t) {
    const unsigned short* vp = Vh + (size_t)(t * 64 + vj0) * 128 + vd0;
    vr[0] = *(const u16x8*)(vp);
    vr[1] = *(const u16x8*)(vp + 8);
    vr[2] = *(const u16x8*)(vp + 128);
    vr[3] = *(const u16x8*)(vp + 136);
  };
  auto writeV = [&]() {
#pragma unroll
    for (int dd = 0; dd < 8; ++dd) {
      unsigned pk0 = (unsigned)vr[0][dd] | ((unsigned)vr[2][dd] << 16);
      unsigned pk1 = (unsigned)vr[1][dd] | ((unsigned)vr[3][dd] << 16);
      *(unsigned*)&lV[(vd0 + dd) * 72 + vj0] = pk0;
      *(unsigned*)&lV[(vd0 + 8 + dd) * 72 + vj0] = pk1;
    }
  };

  loadV(0);
  stageK(0, 0);
  writeV();
  __syncthreads();

  f32x4 acc_o[2][8];
#pragma unroll
  for (int mi = 0; mi < 2; ++mi)
#pragma unroll
    for (int i = 0; i < 8; ++i) acc_o[mi][i] = f32x4{0.f, 0.f, 0.f, 0.f};
  float mrun[2], lrun[2];
#pragma unroll
  for (int mi = 0; mi < 2; ++mi) { mrun[mi] = -__builtin_inff(); lrun[mi] = 0.f; }

  const float SL2E = 0.12751744f;
  const int qrow0 = qb * 128 + w * 32;
  const int srcA = l15 + 16 * ((2 * g) & 3);      // shfl sources (same l15)
  const int srcB = l15 + 16 * ((2 * g + 1) & 3);
  const bool ghi = (g & 2) != 0;                  // g>>1 selects jb parity

  int cur = 0;
  for (int t = 0; t < nt; ++t) {
    const int kv0 = t * 64;
    const bool pre = (t + 1 < nt);
    if (pre) { loadV(t + 1); stageK(t + 1, cur ^ 1); }

    const bool active = (kv0 <= qrow0 + 31);
    if (active) {
      const unsigned short* lKc = &lK[cur][0];
      f32x4 sacc[4][2];
#pragma unroll
      for (int jb = 0; jb < 4; ++jb) {
        sacc[jb][0] = f32x4{0.f, 0.f, 0.f, 0.f};
        sacc[jb][1] = f32x4{0.f, 0.f, 0.f, 0.f};
      }
      __builtin_amdgcn_s_setprio(1);
#pragma unroll
      for (int jb = 0; jb < 4; ++jb) {
        const int r = jb * 16 + l15;
#pragma unroll
        for (int ks = 0; ks < 4; ++ks) {
          const int s = ks * 4 + g;
          bf16x8 kf = *(const bf16x8*)&lKc[r * 128 + (s ^ (r & 7)) * 8];
          sacc[jb][0] = MFMA16(kf, qf[0][ks], sacc[jb][0]);
          sacc[jb][1] = MFMA16(kf, qf[1][ks], sacc[jb][1]);
        }
      }
      __builtin_amdgcn_s_setprio(0);

      const bool need_mask = (kv0 + 63 >= qrow0);
      float psc_l[2];
      bool defer_mi[2];
      unsigned pws[2][4][2];                  // packed P words (static idx only)
#pragma unroll
      for (int mi = 0; mi < 2; ++mi) {
        const int icol = qrow0 + mi * 16 + l15;
        f32x4 pe[4];
#pragma unroll
        for (int jb = 0; jb < 4; ++jb) {
#pragma unroll
          for (int rr = 0; rr < 4; ++rr) {
            float tv = sacc[jb][mi][rr] * SL2E;
            if (need_mask && (kv0 + jb * 16 + g * 4 + rr > icol))
              tv = -__builtin_inff();
            pe[jb][rr] = tv;
          }
        }
        f32x4 m4 = f32x4{fmaxf(fmaxf(pe[0][0], pe[1][0]), fmaxf(pe[2][0], pe[3][0])),
                         fmaxf(fmaxf(pe[0][1], pe[1][1]), fmaxf(pe[2][1], pe[3][1])),
                         fmaxf(fmaxf(pe[0][2], pe[1][2]), fmaxf(pe[2][2], pe[3][2])),
                         fmaxf(fmaxf(pe[0][3], pe[1][3]), fmaxf(pe[2][3], pe[3][3]))};
        float mx = fmaxf(fmaxf(m4[0], m4[1]), fmaxf(m4[2], m4[3]));
        mx = fmaxf(mx, __shfl_xor(mx, 16));
        mx = fmaxf(mx, __shfl_xor(mx, 32));
        // T13: defer the max update when growth <= 8 (wave-uniform)
        const bool dfr = (__all(mx - mrun[mi] <= 8.0f) != 0);
        defer_mi[mi] = dfr;
        if (dfr) {
          psc_l[mi] = 1.0f;
        } else {
          const float mnew = fmaxf(mrun[mi], mx);
          psc_l[mi] = exp2f(mrun[mi] - mnew);
          mrun[mi] = mnew;
        }
        float rs = 0.f;
#pragma unroll
        for (int jb = 0; jb < 4; ++jb) {
#pragma unroll
          for (int rr = 0; rr < 4; ++rr) {
            const float e = exp2f(pe[jb][rr] - mrun[mi]);  // <= 2^8 if deferred
            pe[jb][rr] = e;
            rs += e;
          }
        }
        rs += __shfl_xor(rs, 16);
        rs += __shfl_xor(rs, 32);
        lrun[mi] = lrun[mi] * psc_l[mi] + rs;
#pragma unroll
        for (int jb = 0; jb < 4; ++jb) {
          pws[mi][jb][0] = packbf2(pe[jb][0], pe[jb][1]);
          pws[mi][jb][1] = packbf2(pe[jb][2], pe[jb][3]);
        }
      }

      // rescale acc_o only when not deferred (wave-uniform branch per mi)
#pragma unroll
      for (int mi = 0; mi < 2; ++mi) {
        if (!defer_mi[mi]) {
          float psc_pv[4];
#pragma unroll
          for (int r = 0; r < 4; ++r)
            psc_pv[r] = __shfl(psc_l[mi], g * 4 + r);
#pragma unroll
          for (int nb = 0; nb < 8; ++nb)
#pragma unroll
            for (int r = 0; r < 4; ++r) acc_o[mi][nb][r] *= psc_pv[r];
        }
      }

      // ---- build PV A-frags in-register: dest word w (j=32h+8g+2w,+1) comes
      // from lane srcA (w<2) / srcB (w>=2), jb=2h+(g>>1) -> shfl both jb
      // candidates, select by ghi.
      bf16x8 pa[2][2];
#pragma unroll
      for (int mi = 0; mi < 2; ++mi) {
#pragma unroll
        for (int h = 0; h < 2; ++h) {
          const unsigned a0 = __shfl(pws[mi][2 * h][0], srcA);
          const unsigned a1 = __shfl(pws[mi][2 * h][1], srcA);
          const unsigned a2 = __shfl(pws[mi][2 * h][0], srcB);
          const unsigned a3 = __shfl(pws[mi][2 * h][1], srcB);
          const unsigned b0 = __shfl(pws[mi][2 * h + 1][0], srcA);
          const unsigned b1 = __shfl(pws[mi][2 * h + 1][1], srcA);
          const unsigned b2 = __shfl(pws[mi][2 * h + 1][0], srcB);
          const unsigned b3 = __shfl(pws[mi][2 * h + 1][1], srcB);
          u32x4 wv;
          wv[0] = ghi ? b0 : a0;
          wv[1] = ghi ? b1 : a1;
          wv[2] = ghi ? b2 : a2;
          wv[3] = ghi ? b3 : a3;
          pa[mi][h] = __builtin_bit_cast(bf16x8, wv);
        }
      }

      __builtin_amdgcn_s_setprio(1);
#pragma unroll
      for (int nb = 0; nb < 8; ++nb) {
        const int vrow = nb * 16 + l15;
#pragma unroll
        for (int h = 0; h < 2; ++h) {
          bf16x8 vf = *(const bf16x8*)&lV[vrow * 72 + h * 32 + g * 8];
          acc_o[0][nb] = MFMA16(pa[0][h], vf, acc_o[0][nb]);
          acc_o[1][nb] = MFMA16(pa[1][h], vf, acc_o[1][nb]);
        }
      }
      __builtin_amdgcn_s_setprio(0);
    }

    __syncthreads();
    if (pre) writeV();
    __syncthreads();
    cur ^= 1;
  }

  const int b = bh >> 4, hh = bh & 15;
  float linv[2][4];
#pragma unroll
  for (int mi = 0; mi < 2; ++mi)
#pragma unroll
    for (int r = 0; r < 4; ++r)
      linv[mi][r] = 1.0f / __shfl(lrun[mi], g * 4 + r);
#pragma unroll
  for (int mi = 0; mi < 2; ++mi)
#pragma unroll
    for (int nb = 0; nb < 8; ++nb)
#pragma unroll
      for (int r = 0; r < 4; ++r) {
        const int i = qb * 128 + w * 32 + mi * 16 + g * 4 + r;
        const float o = acc_o[mi][nb][r] * linv[mi][r];
        O[((size_t)(b * 2048 + i)) * 2048 + hh * 128 + nb * 16 + l15] = f2bf(o);
      }
}

// ---------- launch ----------
extern "C" void kernel_launch(void* const* d_in, const int* in_sizes, int n_in,
                              void* d_out, int out_size, void* d_ws, size_t ws_size,
                              hipStream_t stream) {
  const float* x  = (const float*)d_in[0];
  const float* wq = (const float*)d_in[1];
  const float* bq = (const float*)d_in[2];
  const float* wk = (const float*)d_in[3];
  const float* bk = (const float*)d_in[4];
  const float* wv = (const float*)d_in[5];
  const float* bv = (const float*)d_in[6];
  const float* wo = (const float*)d_in[7];
  const float* bo = (const float*)d_in[8];

  const size_t NX = (size_t)2 * 2048 * 2048;
  const size_t NW = (size_t)2048 * 2048;
  const size_t need = (NX + 4 * NW + 3 * NX) * sizeof(unsigned short);  // 96 MB
  if (ws_size < need) return;
  unsigned short* xbf  = (unsigned short*)d_ws;
  unsigned short* wqb  = xbf + NX;
  unsigned short* wkb  = wqb + NW;
  unsigned short* wvb  = wkb + NW;
  unsigned short* wob  = wvb + NW;
  unsigned short* qbuf = wob + NW;
  unsigned short* kbuf = qbuf + NX;
  unsigned short* vbuf = kbuf + NX;
  unsigned short* aobuf = xbf;  // x dead after gemm_qkv (stream-ordered)

  cvt_all<<<dim3(4096, 6), 256, 0, stream>>>(x, wq, wk, wv, wo,
                                             xbf, wqb, wkb, wvb, wob);
  gemm_qkv<<<dim3(16, 16, 3), 512, 0, stream>>>(xbf, wqb, bq, wkb, bk, wvb, bv,
                                                qbuf, kbuf, vbuf);
  attn_fwd<<<dim3(16, 32), 256, 0, stream>>>(qbuf, kbuf, vbuf, aobuf);
  gemm_out<<<dim3(16, 16), 512, 0, stream>>>(aobuf, wob, bo, (float*)d_out);
}

// Round 16
// 267.626 us; speedup vs baseline: 1.3470x; 1.0340x over previous
//
#include <hip/hip_runtime.h>
#include <cstdint>
#include <cstddef>

// ---------- types / helpers ----------
typedef __attribute__((ext_vector_type(8))) short bf16x8;           // 8 bf16 = 4 VGPR
typedef __attribute__((ext_vector_type(8))) unsigned short u16x8;   // raw 16B load
typedef __attribute__((ext_vector_type(4))) unsigned short u16x4;   // 8B store
typedef __attribute__((ext_vector_type(2))) unsigned u32x2;         // 8B LDS store
typedef __attribute__((ext_vector_type(4))) float f32x4;            // MFMA C/D

#define MFMA16(A, B, C) __builtin_amdgcn_mfma_f32_16x16x32_bf16((A), (B), (C), 0, 0, 0)

__device__ __forceinline__ unsigned short f2bf(float f) {
  unsigned u = __builtin_bit_cast(unsigned, f);
  u += 0x7FFFu + ((u >> 16) & 1u);   // RNE
  return (unsigned short)(u >> 16);
}
__device__ __forceinline__ unsigned packbf2(float lo, float hi) {  // 2xbf16 RNE
  unsigned ul = __builtin_bit_cast(unsigned, lo);
  unsigned uh = __builtin_bit_cast(unsigned, hi);
  ul += 0x7FFFu + ((ul >> 16) & 1u);
  uh += 0x7FFFu + ((uh >> 16) & 1u);
  return (ul >> 16) | (uh & 0xffff0000u);
}

// global -> LDS async, 16B/lane. LDS dest wave-uniform (HW adds lane*16).
__device__ __forceinline__ void gload_lds16(const void* gsrc, void* ldst) {
  __builtin_amdgcn_global_load_lds(
      (const __attribute__((address_space(1))) unsigned int*)gsrc,
      (__attribute__((address_space(3))) unsigned int*)ldst,
      16, 0, 0);
}

// ---------- fused f32 -> bf16 down-convert (1 launch for x + 4 weights) ----------
__global__ __launch_bounds__(256) void cvt_all(
    const float* __restrict__ sx, const float* __restrict__ s1,
    const float* __restrict__ s2, const float* __restrict__ s3,
    const float* __restrict__ s4,
    unsigned short* __restrict__ dx, unsigned short* __restrict__ d1,
    unsigned short* __restrict__ d2, unsigned short* __restrict__ d3,
    unsigned short* __restrict__ d4) {
  const int y = blockIdx.y;
  const float* src;
  unsigned short* dst;
  if (y == 0)      { src = sx;               dst = dx; }
  else if (y == 1) { src = sx + (1u << 22);  dst = dx + (1u << 22); }
  else if (y == 2) { src = s1; dst = d1; }
  else if (y == 3) { src = s2; dst = d2; }
  else if (y == 4) { src = s3; dst = d3; }
  else             { src = s4; dst = d4; }
  const size_t i = ((size_t)blockIdx.x * 256 + threadIdx.x) * 4;
  f32x4 v = *(const f32x4*)(src + i);
  u16x4 o;
  o[0] = f2bf(v[0]); o[1] = f2bf(v[1]); o[2] = f2bf(v[2]); o[3] = f2bf(v[3]);
  *(u16x4*)(dst + i) = o;
}

// ---------- counted-vmcnt GEMM, 1 barrier per K-tile (r13-proven) ----------
// BM=256, BN=128, BK=64; 8 waves (4M x 2N), per-wave 64x64 (acc[4][4]).
// Triple-buffered LDS (144KB): stage kt+2 while computing kt; vmcnt(6) at the
// single end-of-tile barrier (T4: never 0 mid-loop).
// T2 XOR-swizzle (elem ^= (row&7)<<3) on gload SOURCE + ds_read (rule #21).
// MODE 0: C row-major f32. MODE 1: QKV head-permute bf16, LDS-staged coalesced.
template <int MODE>
__device__ __forceinline__ void gemm8_tile(const unsigned short* __restrict__ A,
                                           const unsigned short* __restrict__ W,
                                           const float* __restrict__ bias,
                                           void* __restrict__ C,
                                           int bx, int by) {
  constexpr int K = 2048, N = 2048;
  constexpr int NT = K / 64;                  // 32 K-tiles
  __shared__ __align__(16) unsigned short lA[3][256 * 64];  // 96KB
  __shared__ __align__(16) unsigned short lB[3][128 * 64];  // 48KB
  const int tid = threadIdx.x;
  const int lane = tid & 63;
  const int w = tid >> 6;                     // 0..7
  const int g = lane >> 4;
  const int l15 = lane & 15;
  const int wm = w >> 1, wn = w & 1;
  const int m0 = by * 256, n0 = bx * 128;

  auto stageA = [&](int kt, int buf) {        // 4 gloads: 256x64 = 2048 slots
    const int kb = kt * 64;
#pragma unroll
    for (int it = 0; it < 4; ++it) {
      const int f = it * 512 + tid;
      const int r = f >> 3, s = f & 7;
      gload_lds16(A + (size_t)(m0 + r) * K + kb + ((s * 8) ^ ((r & 7) << 3)),
                  (char*)&lA[buf][0] + (it * 512 + w * 64) * 16);
    }
  };
  auto stageB = [&](int kt, int buf) {        // 2 gloads: 128x64 = 1024 slots
    const int kb = kt * 64;
#pragma unroll
    for (int it = 0; it < 2; ++it) {
      const int f = it * 512 + tid;
      const int r = f >> 3, s = f & 7;
      gload_lds16(W + (size_t)(n0 + r) * K + kb + ((s * 8) ^ ((r & 7) << 3)),
                  (char*)&lB[buf][0] + (it * 512 + w * 64) * 16);
    }
  };

  f32x4 acc[4][4];
#pragma unroll
  for (int i = 0; i < 4; ++i)
#pragma unroll
    for (int j = 0; j < 4; ++j) acc[i][j] = f32x4{0.f, 0.f, 0.f, 0.f};

  // ---- prologue: tiles 0,1 -> bufs 0,1; wait tile0 (6 of 12 retire)
  stageA(0, 0); stageB(0, 0);
  stageA(1, 1); stageB(1, 1);
  asm volatile("s_waitcnt vmcnt(6)" ::: "memory");
  __builtin_amdgcn_s_barrier();
  __builtin_amdgcn_sched_barrier(0);

  int cur = 0, nxt = 2;
  for (int kt = 0; kt < NT; ++kt) {
    const unsigned short* As = &lA[cur][0];
    const unsigned short* Bs = &lB[cur][0];
    bf16x8 bfr[4][2], af[4][2];
#pragma unroll
    for (int ni = 0; ni < 4; ++ni) {
      const int rb = wn * 64 + ni * 16 + l15;
#pragma unroll
      for (int kh = 0; kh < 2; ++kh)
        bfr[ni][kh] =
            *(const bf16x8*)&Bs[rb * 64 + ((kh * 32 + g * 8) ^ ((rb & 7) << 3))];
    }
#pragma unroll
    for (int mi = 0; mi < 4; ++mi) {
      const int ra = wm * 64 + mi * 16 + l15;
#pragma unroll
      for (int kh = 0; kh < 2; ++kh)
        af[mi][kh] =
            *(const bf16x8*)&As[ra * 64 + ((kh * 32 + g * 8) ^ ((ra & 7) << 3))];
    }
    if (kt + 2 < NT) { stageA(kt + 2, nxt); stageB(kt + 2, nxt); }
    __builtin_amdgcn_s_setprio(1);
#pragma unroll
    for (int kh = 0; kh < 2; ++kh)
#pragma unroll
      for (int mi = 0; mi < 4; ++mi)
#pragma unroll
        for (int ni = 0; ni < 4; ++ni)
          acc[mi][ni] = MFMA16(af[mi][kh], bfr[ni][kh], acc[mi][ni]);
    __builtin_amdgcn_s_setprio(0);
    // single end-of-tile sync: tile kt+1 resident, kt+2's 6 loads in flight.
    if (kt < NT - 2)       asm volatile("s_waitcnt vmcnt(6)" ::: "memory");
    else if (kt == NT - 2) asm volatile("s_waitcnt vmcnt(0)" ::: "memory");
    __builtin_amdgcn_s_barrier();
    __builtin_amdgcn_sched_barrier(0);
    cur = (cur == 2) ? 0 : cur + 1;
    nxt = (nxt == 2) ? 0 : nxt + 1;
  }

  // ---- epilogue: D layout col=lane&15 (n), row=4g+rr (m)
  if (MODE == 0) {
#pragma unroll
    for (int ni = 0; ni < 4; ++ni) {
      const int n = n0 + wn * 64 + ni * 16 + l15;
      const float bval = bias[n];
#pragma unroll
      for (int mi = 0; mi < 4; ++mi) {
        const int mb = m0 + wm * 64 + mi * 16 + g * 4;
#pragma unroll
        for (int r = 0; r < 4; ++r)
          ((float*)C)[(size_t)(mb + r) * N + n] = acc[mi][ni][r] + bval;
      }
    }
  } else {
    // stage 256x128 bf16 C-tile in dead lA (64KB), then coalesced b128 stores
    unsigned short* lc = &lA[0][0];
#pragma unroll
    for (int ni = 0; ni < 4; ++ni) {
      const int n = n0 + wn * 64 + ni * 16 + l15;
      const float bval = bias[n];
      const int col = wn * 64 + ni * 16 + l15;
#pragma unroll
      for (int mi = 0; mi < 4; ++mi) {
        const int rbase = wm * 64 + mi * 16 + g * 4;
#pragma unroll
        for (int r = 0; r < 4; ++r)
          lc[(rbase + r) * 128 + col] = f2bf(acc[mi][ni][r] + bval);
      }
    }
    __syncthreads();
    const int bb = m0 >> 11;                   // constant per block
    const int hh = n0 >> 7;                    // constant per block
    unsigned short* dst = (unsigned short*)C +
        (((size_t)(bb * 16 + hh) * 2048) + (m0 & 2047)) * 128;
#pragma unroll
    for (int p = 0; p < 8; ++p) {
      const int f = p * 512 + tid;             // 4096 slots of 8 u16
      const int row = f >> 4, slot = f & 15;
      *(u16x8*)(dst + (size_t)row * 128 + slot * 8) =
          *(const u16x8*)&lc[row * 128 + slot * 8];
    }
  }
}

// T1 XCD-aware bijective remap: blocks resident on one XCD (o%8 const) cover a
// compact by-major tile range -> A-panels L2-local, working set L3-local.
__global__ __launch_bounds__(512, 2) void gemm_qkv(
    const unsigned short* __restrict__ x,
    const unsigned short* __restrict__ wq, const float* __restrict__ bq,
    const unsigned short* __restrict__ wk, const float* __restrict__ bk,
    const unsigned short* __restrict__ wv, const float* __restrict__ bv,
    unsigned short* __restrict__ qo, unsigned short* __restrict__ ko,
    unsigned short* __restrict__ vo) {
  const int o = blockIdx.x + ((int)blockIdx.y << 4) + ((int)blockIdx.z << 8);
  const int t = (o & 7) * 96 + (o >> 3);      // 768 = 8 x 96, bijective
  const int z = t >> 8;
  const int by = (t & 255) >> 4;
  const int bx = t & 15;
  const unsigned short* W = (z == 0) ? wq : (z == 1) ? wk : wv;
  const float* B = (z == 0) ? bq : (z == 1) ? bk : bv;
  unsigned short* O = (z == 0) ? qo : (z == 1) ? ko : vo;
  gemm8_tile<1>(x, W, B, O, bx, by);
}

__global__ __launch_bounds__(512, 2) void gemm_out(
    const unsigned short* __restrict__ A, const unsigned short* __restrict__ wo,
    const float* __restrict__ bo, float* __restrict__ C) {
  const int o = blockIdx.x + ((int)blockIdx.y << 4);
  const int t = (o & 7) * 32 + (o >> 3);      // 256 = 8 x 32, bijective
  const int by = t >> 4;
  const int bx = t & 15;
  gemm8_tile<0>(A, wo, bo, C, bx, by);
}

// ---------- causal flash attention, swapped-QK^T in-lane softmax ----------
// r13-proven best: lP b64-packed stores (bank-uniform), sched_barrier fence,
// T13 defer-rescale, (256,2). In-reg-P variants measured slower (r14 spill,
// r15 shuffle-chain cost) -- this structure is the keeper.
__global__ __launch_bounds__(256, 2) void attn_fwd(
    const unsigned short* __restrict__ Q, const unsigned short* __restrict__ K,
    const unsigned short* __restrict__ V, unsigned short* __restrict__ O) {
  __shared__ unsigned short lK[2][64 * 128];  // 32KB dbuf (swizzled slots)
  __shared__ unsigned short lV[128 * 72];     // V^T [d][j], 144B rows
  __shared__ unsigned short lP[4][32 * 72];   // per-wave P [i][j], 144B rows
  const int tid = threadIdx.x;
  const int lane = tid & 63;
  const int w = tid >> 6;
  const int g = lane >> 4;
  const int l15 = lane & 15;
  const int bx = blockIdx.x;
  const int bh = blockIdx.y;
  const int qb = (bh >= 16) ? (15 - bx) : bx;  // CU-pair balance
  const int nt = 2 * qb + 2;
  const size_t head_off = (size_t)bh * 2048 * 128;
  const unsigned short* Qh = Q + head_off;
  const unsigned short* Kh = K + head_off;
  const unsigned short* Vh = V + head_off;

  bf16x8 qf[2][4];
#pragma unroll
  for (int mi = 0; mi < 2; ++mi) {
    const int row = qb * 128 + w * 32 + mi * 16 + l15;
#pragma unroll
    for (int ks = 0; ks < 4; ++ks) {
      const int s = ks * 4 + g;
      qf[mi][ks] = *(const bf16x8*)(Qh + (size_t)row * 128 + s * 8);
    }
  }

  const int vj0 = (tid & 31) * 2;
  const int vd0 = (tid >> 5) * 16;
  u16x8 vr[4];

  auto stageK = [&](int t, int buf) {
#pragma unroll
    for (int it = 0; it < 4; ++it) {
      const int f = it * 256 + tid;
      const int r = f >> 4, s = f & 15;
      const int sc = s ^ (r & 7);
      gload_lds16(Kh + (size_t)(t * 64 + r) * 128 + sc * 8,
                  (char*)&lK[buf][0] + (it * 256 + w * 64) * 16);
    }
  };
  auto loadV = [&](int t) {
    const unsigned short* vp = Vh + (size_t)(t * 64 + vj0) * 128 + vd0;
    vr[0] = *(const u16x8*)(vp);
    vr[1] = *(const u16x8*)(vp + 8);
    vr[2] = *(const u16x8*)(vp + 128);
    vr[3] = *(const u16x8*)(vp + 136);
  };
  auto writeV = [&]() {
#pragma unroll
    for (int dd = 0; dd < 8; ++dd) {
      unsigned pk0 = (unsigned)vr[0][dd] | ((unsigned)vr[2][dd] << 16);
      unsigned pk1 = (unsigned)vr[1][dd] | ((unsigned)vr[3][dd] << 16);
      *(unsigned*)&lV[(vd0 + dd) * 72 + vj0] = pk0;
      *(unsigned*)&lV[(vd0 + 8 + dd) * 72 + vj0] = pk1;
    }
  };

  loadV(0);
  stageK(0, 0);
  writeV();
  __syncthreads();

  f32x4 acc_o[2][8];
#pragma unroll
  for (int mi = 0; mi < 2; ++mi)
#pragma unroll
    for (int i = 0; i < 8; ++i) acc_o[mi][i] = f32x4{0.f, 0.f, 0.f, 0.f};
  float mrun[2], lrun[2];
#pragma unroll
  for (int mi = 0; mi < 2; ++mi) { mrun[mi] = -__builtin_inff(); lrun[mi] = 0.f; }

  const float SL2E = 0.12751744f;
  const int qrow0 = qb * 128 + w * 32;

  int cur = 0;
  for (int t = 0; t < nt; ++t) {
    const int kv0 = t * 64;
    const bool pre = (t + 1 < nt);
    if (pre) { loadV(t + 1); stageK(t + 1, cur ^ 1); }

    const bool active = (kv0 <= qrow0 + 31);
    if (active) {
      const unsigned short* lKc = &lK[cur][0];
      f32x4 sacc[4][2];
#pragma unroll
      for (int jb = 0; jb < 4; ++jb) {
        sacc[jb][0] = f32x4{0.f, 0.f, 0.f, 0.f};
        sacc[jb][1] = f32x4{0.f, 0.f, 0.f, 0.f};
      }
      __builtin_amdgcn_s_setprio(1);
#pragma unroll
      for (int jb = 0; jb < 4; ++jb) {
        const int r = jb * 16 + l15;
#pragma unroll
        for (int ks = 0; ks < 4; ++ks) {
          const int s = ks * 4 + g;
          bf16x8 kf = *(const bf16x8*)&lKc[r * 128 + (s ^ (r & 7)) * 8];
          sacc[jb][0] = MFMA16(kf, qf[0][ks], sacc[jb][0]);
          sacc[jb][1] = MFMA16(kf, qf[1][ks], sacc[jb][1]);
        }
      }
      __builtin_amdgcn_s_setprio(0);

      const bool need_mask = (kv0 + 63 >= qrow0);
      float psc_l[2];
      bool defer_mi[2];
#pragma unroll
      for (int mi = 0; mi < 2; ++mi) {
        const int icol = qrow0 + mi * 16 + l15;
        f32x4 pe[4];
#pragma unroll
        for (int jb = 0; jb < 4; ++jb) {
#pragma unroll
          for (int rr = 0; rr < 4; ++rr) {
            float tv = sacc[jb][mi][rr] * SL2E;
            if (need_mask && (kv0 + jb * 16 + g * 4 + rr > icol))
              tv = -__builtin_inff();
            pe[jb][rr] = tv;
          }
        }
        f32x4 m4 = f32x4{fmaxf(fmaxf(pe[0][0], pe[1][0]), fmaxf(pe[2][0], pe[3][0])),
                         fmaxf(fmaxf(pe[0][1], pe[1][1]), fmaxf(pe[2][1], pe[3][1])),
                         fmaxf(fmaxf(pe[0][2], pe[1][2]), fmaxf(pe[2][2], pe[3][2])),
                         fmaxf(fmaxf(pe[0][3], pe[1][3]), fmaxf(pe[2][3], pe[3][3]))};
        float mx = fmaxf(fmaxf(m4[0], m4[1]), fmaxf(m4[2], m4[3]));
        mx = fmaxf(mx, __shfl_xor(mx, 16));
        mx = fmaxf(mx, __shfl_xor(mx, 32));
        // T13: defer the max update when growth <= 8 (wave-uniform; first
        // tile has mrun=-inf -> inf > 8 -> full path automatically).
        const bool dfr = (__all(mx - mrun[mi] <= 8.0f) != 0);
        defer_mi[mi] = dfr;
        if (dfr) {
          psc_l[mi] = 1.0f;                   // keep old max, no rescale
        } else {
          const float mnew = fmaxf(mrun[mi], mx);
          psc_l[mi] = exp2f(mrun[mi] - mnew); // 0 on first tile
          mrun[mi] = mnew;
        }
        float rs = 0.f;
#pragma unroll
        for (int jb = 0; jb < 4; ++jb) {
#pragma unroll
          for (int rr = 0; rr < 4; ++rr) {
            const float e = exp2f(pe[jb][rr] - mrun[mi]);  // <= 2^8 if deferred
            pe[jb][rr] = e;
            rs += e;
          }
        }
        rs += __shfl_xor(rs, 16);
        rs += __shfl_xor(rs, 32);
        lrun[mi] = lrun[mi] * psc_l[mi] + rs;
        // ---- P -> per-wave LDS: b64 packed (4 consecutive j per store)
#pragma unroll
        for (int jb = 0; jb < 4; ++jb) {
          u32x2 pw;
          pw[0] = packbf2(pe[jb][0], pe[jb][1]);
          pw[1] = packbf2(pe[jb][2], pe[jb][3]);
          *(u32x2*)&lP[w][(mi * 16 + l15) * 72 + jb * 16 + g * 4] = pw;
        }
      }
      // fence: forbid hoisting the pa ds_reads above the lP ds_writes
      __builtin_amdgcn_sched_barrier(0);

      // rescale acc_o only when not deferred (wave-uniform branch per mi)
#pragma unroll
      for (int mi = 0; mi < 2; ++mi) {
        if (!defer_mi[mi]) {
          float psc_pv[4];
#pragma unroll
          for (int r = 0; r < 4; ++r)
            psc_pv[r] = __shfl(psc_l[mi], g * 4 + r);
#pragma unroll
          for (int nb = 0; nb < 8; ++nb)
#pragma unroll
            for (int r = 0; r < 4; ++r) acc_o[mi][nb][r] *= psc_pv[r];
        }
      }

      bf16x8 pa[2][2];
#pragma unroll
      for (int mi = 0; mi < 2; ++mi)
#pragma unroll
        for (int h = 0; h < 2; ++h)
          pa[mi][h] = *(const bf16x8*)&lP[w][(mi * 16 + l15) * 72 + h * 32 + g * 8];
      __builtin_amdgcn_s_setprio(1);
#pragma unroll
      for (int nb = 0; nb < 8; ++nb) {
        const int vrow = nb * 16 + l15;
#pragma unroll
        for (int h = 0; h < 2; ++h) {
          bf16x8 vf = *(const bf16x8*)&lV[vrow * 72 + h * 32 + g * 8];
          acc_o[0][nb] = MFMA16(pa[0][h], vf, acc_o[0][nb]);
          acc_o[1][nb] = MFMA16(pa[1][h], vf, acc_o[1][nb]);
        }
      }
      __builtin_amdgcn_s_setprio(0);
    }

    __syncthreads();
    if (pre) writeV();
    __syncthreads();
    cur ^= 1;
  }

  const int b = bh >> 4, hh = bh & 15;
  float linv[2][4];
#pragma unroll
  for (int mi = 0; mi < 2; ++mi)
#pragma unroll
    for (int r = 0; r < 4; ++r)
      linv[mi][r] = 1.0f / __shfl(lrun[mi], g * 4 + r);
#pragma unroll
  for (int mi = 0; mi < 2; ++mi)
#pragma unroll
    for (int nb = 0; nb < 8; ++nb)
#pragma unroll
      for (int r = 0; r < 4; ++r) {
        const int i = qb * 128 + w * 32 + mi * 16 + g * 4 + r;
        const float o = acc_o[mi][nb][r] * linv[mi][r];
        O[((size_t)(b * 2048 + i)) * 2048 + hh * 128 + nb * 16 + l15] = f2bf(o);
      }
}

// ---------- launch ----------
extern "C" void kernel_launch(void* const* d_in, const int* in_sizes, int n_in,
                              void* d_out, int out_size, void* d_ws, size_t ws_size,
                              hipStream_t stream) {
  const float* x  = (const float*)d_in[0];
  const float* wq = (const float*)d_in[1];
  const float* bq = (const float*)d_in[2];
  const float* wk = (const float*)d_in[3];
  const float* bk = (const float*)d_in[4];
  const float* wv = (const float*)d_in[5];
  const float* bv = (const float*)d_in[6];
  const float* wo = (const float*)d_in[7];
  const float* bo = (const float*)d_in[8];

  const size_t NX = (size_t)2 * 2048 * 2048;
  const size_t NW = (size_t)2048 * 2048;
  const size_t need = (NX + 4 * NW + 3 * NX) * sizeof(unsigned short);  // 96 MB
  if (ws_size < need) return;
  unsigned short* xbf  = (unsigned short*)d_ws;
  unsigned short* wqb  = xbf + NX;
  unsigned short* wkb  = wqb + NW;
  unsigned short* wvb  = wkb + NW;
  unsigned short* wob  = wvb + NW;
  unsigned short* qbuf = wob + NW;
  unsigned short* kbuf = qbuf + NX;
  unsigned short* vbuf = kbuf + NX;
  unsigned short* aobuf = xbf;  // x dead after gemm_qkv (stream-ordered)

  cvt_all<<<dim3(4096, 6), 256, 0, stream>>>(x, wq, wk, wv, wo,
                                             xbf, wqb, wkb, wvb, wob);
  gemm_qkv<<<dim3(16, 16, 3), 512, 0, stream>>>(xbf, wqb, bq, wkb, bk, wvb, bv,
                                                qbuf, kbuf, vbuf);
  attn_fwd<<<dim3(16, 32), 256, 0, stream>>>(qbuf, kbuf, vbuf, aobuf);
  gemm_out<<<dim3(16, 16), 512, 0, stream>>>(aobuf, wob, bo, (float*)d_out);
}

// Round 17
// 265.387 us; speedup vs baseline: 1.3584x; 1.0084x over previous
//
#include <hip/hip_runtime.h>
#include <cstdint>
#include <cstddef>

// ---------- types / helpers ----------
typedef __attribute__((ext_vector_type(8))) short bf16x8;           // 8 bf16 = 4 VGPR
typedef __attribute__((ext_vector_type(8))) unsigned short u16x8;   // raw 16B load
typedef __attribute__((ext_vector_type(4))) unsigned short u16x4;   // 8B store
typedef __attribute__((ext_vector_type(2))) unsigned u32x2;         // 8B LDS store
typedef __attribute__((ext_vector_type(4))) float f32x4;            // MFMA C/D

#define MFMA16(A, B, C) __builtin_amdgcn_mfma_f32_16x16x32_bf16((A), (B), (C), 0, 0, 0)

__device__ __forceinline__ unsigned short f2bf(float f) {
  unsigned u = __builtin_bit_cast(unsigned, f);
  u += 0x7FFFu + ((u >> 16) & 1u);   // RNE
  return (unsigned short)(u >> 16);
}
__device__ __forceinline__ unsigned packbf2(float lo, float hi) {  // 2xbf16 RNE
  unsigned ul = __builtin_bit_cast(unsigned, lo);
  unsigned uh = __builtin_bit_cast(unsigned, hi);
  ul += 0x7FFFu + ((ul >> 16) & 1u);
  uh += 0x7FFFu + ((uh >> 16) & 1u);
  return (ul >> 16) | (uh & 0xffff0000u);
}

// global -> LDS async, 16B/lane. LDS dest wave-uniform (HW adds lane*16).
__device__ __forceinline__ void gload_lds16(const void* gsrc, void* ldst) {
  __builtin_amdgcn_global_load_lds(
      (const __attribute__((address_space(1))) unsigned int*)gsrc,
      (__attribute__((address_space(3))) unsigned int*)ldst,
      16, 0, 0);
}

// ---------- fused f32 -> bf16 down-convert (1 launch for x + 4 weights) ----------
__global__ __launch_bounds__(256) void cvt_all(
    const float* __restrict__ sx, const float* __restrict__ s1,
    const float* __restrict__ s2, const float* __restrict__ s3,
    const float* __restrict__ s4,
    unsigned short* __restrict__ dx, unsigned short* __restrict__ d1,
    unsigned short* __restrict__ d2, unsigned short* __restrict__ d3,
    unsigned short* __restrict__ d4) {
  const int y = blockIdx.y;
  const float* src;
  unsigned short* dst;
  if (y == 0)      { src = sx;               dst = dx; }
  else if (y == 1) { src = sx + (1u << 22);  dst = dx + (1u << 22); }
  else if (y == 2) { src = s1; dst = d1; }
  else if (y == 3) { src = s2; dst = d2; }
  else if (y == 4) { src = s3; dst = d3; }
  else             { src = s4; dst = d4; }
  const size_t i = ((size_t)blockIdx.x * 256 + threadIdx.x) * 4;
  f32x4 v = *(const f32x4*)(src + i);
  u16x4 o;
  o[0] = f2bf(v[0]); o[1] = f2bf(v[1]); o[2] = f2bf(v[2]); o[3] = f2bf(v[3]);
  *(u16x4*)(dst + i) = o;
}

// ---------- counted-vmcnt GEMM, 1 barrier per K-tile (r13-proven) ----------
// BM=256, BN=128, BK=64; 8 waves (4M x 2N), per-wave 64x64 (acc[4][4]).
// Triple-buffered LDS (144KB): stage kt+2 while computing kt; vmcnt(6) at the
// single end-of-tile barrier (T4: never 0 mid-loop).
// T2 XOR-swizzle (elem ^= (row&7)<<3) on gload SOURCE + ds_read (rule #21).
// MODE 0: C row-major f32. MODE 1: QKV head-permute bf16, LDS-staged coalesced.
template <int MODE>
__device__ __forceinline__ void gemm8_tile(const unsigned short* __restrict__ A,
                                           const unsigned short* __restrict__ W,
                                           const float* __restrict__ bias,
                                           void* __restrict__ C,
                                           int bx, int by) {
  constexpr int K = 2048, N = 2048;
  constexpr int NT = K / 64;                  // 32 K-tiles
  __shared__ __align__(16) unsigned short lA[3][256 * 64];  // 96KB
  __shared__ __align__(16) unsigned short lB[3][128 * 64];  // 48KB
  const int tid = threadIdx.x;
  const int lane = tid & 63;
  const int w = tid >> 6;                     // 0..7
  const int g = lane >> 4;
  const int l15 = lane & 15;
  const int wm = w >> 1, wn = w & 1;
  const int m0 = by * 256, n0 = bx * 128;

  auto stageA = [&](int kt, int buf) {        // 4 gloads: 256x64 = 2048 slots
    const int kb = kt * 64;
#pragma unroll
    for (int it = 0; it < 4; ++it) {
      const int f = it * 512 + tid;
      const int r = f >> 3, s = f & 7;
      gload_lds16(A + (size_t)(m0 + r) * K + kb + ((s * 8) ^ ((r & 7) << 3)),
                  (char*)&lA[buf][0] + (it * 512 + w * 64) * 16);
    }
  };
  auto stageB = [&](int kt, int buf) {        // 2 gloads: 128x64 = 1024 slots
    const int kb = kt * 64;
#pragma unroll
    for (int it = 0; it < 2; ++it) {
      const int f = it * 512 + tid;
      const int r = f >> 3, s = f & 7;
      gload_lds16(W + (size_t)(n0 + r) * K + kb + ((s * 8) ^ ((r & 7) << 3)),
                  (char*)&lB[buf][0] + (it * 512 + w * 64) * 16);
    }
  };

  f32x4 acc[4][4];
#pragma unroll
  for (int i = 0; i < 4; ++i)
#pragma unroll
    for (int j = 0; j < 4; ++j) acc[i][j] = f32x4{0.f, 0.f, 0.f, 0.f};

  // ---- prologue: tiles 0,1 -> bufs 0,1; wait tile0 (6 of 12 retire)
  stageA(0, 0); stageB(0, 0);
  stageA(1, 1); stageB(1, 1);
  asm volatile("s_waitcnt vmcnt(6)" ::: "memory");
  __builtin_amdgcn_s_barrier();
  __builtin_amdgcn_sched_barrier(0);

  int cur = 0, nxt = 2;
  for (int kt = 0; kt < NT; ++kt) {
    const unsigned short* As = &lA[cur][0];
    const unsigned short* Bs = &lB[cur][0];
    bf16x8 bfr[4][2], af[4][2];
#pragma unroll
    for (int ni = 0; ni < 4; ++ni) {
      const int rb = wn * 64 + ni * 16 + l15;
#pragma unroll
      for (int kh = 0; kh < 2; ++kh)
        bfr[ni][kh] =
            *(const bf16x8*)&Bs[rb * 64 + ((kh * 32 + g * 8) ^ ((rb & 7) << 3))];
    }
#pragma unroll
    for (int mi = 0; mi < 4; ++mi) {
      const int ra = wm * 64 + mi * 16 + l15;
#pragma unroll
      for (int kh = 0; kh < 2; ++kh)
        af[mi][kh] =
            *(const bf16x8*)&As[ra * 64 + ((kh * 32 + g * 8) ^ ((ra & 7) << 3))];
    }
    if (kt + 2 < NT) { stageA(kt + 2, nxt); stageB(kt + 2, nxt); }
    __builtin_amdgcn_s_setprio(1);
#pragma unroll
    for (int kh = 0; kh < 2; ++kh)
#pragma unroll
      for (int mi = 0; mi < 4; ++mi)
#pragma unroll
        for (int ni = 0; ni < 4; ++ni)
          acc[mi][ni] = MFMA16(af[mi][kh], bfr[ni][kh], acc[mi][ni]);
    __builtin_amdgcn_s_setprio(0);
    // single end-of-tile sync: tile kt+1 resident, kt+2's 6 loads in flight.
    if (kt < NT - 2)       asm volatile("s_waitcnt vmcnt(6)" ::: "memory");
    else if (kt == NT - 2) asm volatile("s_waitcnt vmcnt(0)" ::: "memory");
    __builtin_amdgcn_s_barrier();
    __builtin_amdgcn_sched_barrier(0);
    cur = (cur == 2) ? 0 : cur + 1;
    nxt = (nxt == 2) ? 0 : nxt + 1;
  }

  // ---- epilogue: D layout col=lane&15 (n), row=4g+rr (m)
  if (MODE == 0) {
#pragma unroll
    for (int ni = 0; ni < 4; ++ni) {
      const int n = n0 + wn * 64 + ni * 16 + l15;
      const float bval = bias[n];
#pragma unroll
      for (int mi = 0; mi < 4; ++mi) {
        const int mb = m0 + wm * 64 + mi * 16 + g * 4;
#pragma unroll
        for (int r = 0; r < 4; ++r)
          ((float*)C)[(size_t)(mb + r) * N + n] = acc[mi][ni][r] + bval;
      }
    }
  } else {
    // stage 256x128 bf16 C-tile in dead lA (64KB), then coalesced b128 stores
    unsigned short* lc = &lA[0][0];
#pragma unroll
    for (int ni = 0; ni < 4; ++ni) {
      const int n = n0 + wn * 64 + ni * 16 + l15;
      const float bval = bias[n];
      const int col = wn * 64 + ni * 16 + l15;
#pragma unroll
      for (int mi = 0; mi < 4; ++mi) {
        const int rbase = wm * 64 + mi * 16 + g * 4;
#pragma unroll
        for (int r = 0; r < 4; ++r)
          lc[(rbase + r) * 128 + col] = f2bf(acc[mi][ni][r] + bval);
      }
    }
    __syncthreads();
    const int bb = m0 >> 11;                   // constant per block
    const int hh = n0 >> 7;                    // constant per block
    unsigned short* dst = (unsigned short*)C +
        (((size_t)(bb * 16 + hh) * 2048) + (m0 & 2047)) * 128;
#pragma unroll
    for (int p = 0; p < 8; ++p) {
      const int f = p * 512 + tid;             // 4096 slots of 8 u16
      const int row = f >> 4, slot = f & 15;
      *(u16x8*)(dst + (size_t)row * 128 + slot * 8) =
          *(const u16x8*)&lc[row * 128 + slot * 8];
    }
  }
}

// T1 XCD-aware bijective remap: blocks resident on one XCD (o%8 const) cover a
// compact by-major tile range -> A-panels L2-local, working set L3-local.
__global__ __launch_bounds__(512, 2) void gemm_qkv(
    const unsigned short* __restrict__ x,
    const unsigned short* __restrict__ wq, const float* __restrict__ bq,
    const unsigned short* __restrict__ wk, const float* __restrict__ bk,
    const unsigned short* __restrict__ wv, const float* __restrict__ bv,
    unsigned short* __restrict__ qo, unsigned short* __restrict__ ko,
    unsigned short* __restrict__ vo) {
  const int o = blockIdx.x + ((int)blockIdx.y << 4) + ((int)blockIdx.z << 8);
  const int t = (o & 7) * 96 + (o >> 3);      // 768 = 8 x 96, bijective
  const int z = t >> 8;
  const int by = (t & 255) >> 4;
  const int bx = t & 15;
  const unsigned short* W = (z == 0) ? wq : (z == 1) ? wk : wv;
  const float* B = (z == 0) ? bq : (z == 1) ? bk : bv;
  unsigned short* O = (z == 0) ? qo : (z == 1) ? ko : vo;
  gemm8_tile<1>(x, W, B, O, bx, by);
}

__global__ __launch_bounds__(512, 2) void gemm_out(
    const unsigned short* __restrict__ A, const unsigned short* __restrict__ wo,
    const float* __restrict__ bo, float* __restrict__ C) {
  const int o = blockIdx.x + ((int)blockIdx.y << 4);
  const int t = (o & 7) * 32 + (o >> 3);      // 256 = 8 x 32, bijective
  const int by = t >> 4;
  const int bx = t & 15;
  gemm8_tile<0>(A, wo, bo, C, bx, by);
}

// ---------- causal flash attention: single barrier/tile, lV double-buffered ----
// r13 structure, but lV dbuf'd and lV/lP converted from +8-pad (stride 72) to
// stride-64 + XOR swizzle (elem ^= (row&7)<<3; b32/b64 runs never cross their
// 8-group; reads 8-aligned) -> LDS = 32K lK + 32K lV + 16K lP = 81920 B
// (2 blocks/CU at exactly 160KB). writeV(t+1) targets the buffer last read at
// iter t-1 (protected by that iter's barrier) -> the mid-iter barrier is
// redundant and writeV overlaps PV. One __syncthreads per tile (vmcnt(0) drain
// publishes lK[t+1&1] and lV[t+1&1]).
__global__ __launch_bounds__(256, 2) void attn_fwd(
    const unsigned short* __restrict__ Q, const unsigned short* __restrict__ K,
    const unsigned short* __restrict__ V, unsigned short* __restrict__ O) {
  __shared__ unsigned short lK[2][64 * 128];  // 32KB dbuf (swizzled slots)
  __shared__ unsigned short lV[2][128 * 64];  // 32KB dbuf, swizzled stride-64
  __shared__ unsigned short lP[4][32 * 64];   // 16KB per-wave P, swizzled
  const int tid = threadIdx.x;
  const int lane = tid & 63;
  const int w = tid >> 6;
  const int g = lane >> 4;
  const int l15 = lane & 15;
  const int bx = blockIdx.x;
  const int bh = blockIdx.y;
  const int qb = (bh >= 16) ? (15 - bx) : bx;  // CU-pair balance
  const int nt = 2 * qb + 2;
  const size_t head_off = (size_t)bh * 2048 * 128;
  const unsigned short* Qh = Q + head_off;
  const unsigned short* Kh = K + head_off;
  const unsigned short* Vh = V + head_off;

  bf16x8 qf[2][4];
#pragma unroll
  for (int mi = 0; mi < 2; ++mi) {
    const int row = qb * 128 + w * 32 + mi * 16 + l15;
#pragma unroll
    for (int ks = 0; ks < 4; ++ks) {
      const int s = ks * 4 + g;
      qf[mi][ks] = *(const bf16x8*)(Qh + (size_t)row * 128 + s * 8);
    }
  }

  const int vj0 = (tid & 31) * 2;
  const int vd0 = (tid >> 5) * 16;
  u16x8 vr[4];

  auto stageK = [&](int t, int buf) {
#pragma unroll
    for (int it = 0; it < 4; ++it) {
      const int f = it * 256 + tid;
      const int r = f >> 4, s = f & 15;
      const int sc = s ^ (r & 7);
      gload_lds16(Kh + (size_t)(t * 64 + r) * 128 + sc * 8,
                  (char*)&lK[buf][0] + (it * 256 + w * 64) * 16);
    }
  };
  auto loadV = [&](int t) {
    const unsigned short* vp = Vh + (size_t)(t * 64 + vj0) * 128 + vd0;
    vr[0] = *(const u16x8*)(vp);
    vr[1] = *(const u16x8*)(vp + 8);
    vr[2] = *(const u16x8*)(vp + 128);
    vr[3] = *(const u16x8*)(vp + 136);
  };
  auto writeV = [&](int buf) {                // swizzled stride-64 V^T [d][j]
    unsigned short* lVb = &lV[buf][0];
#pragma unroll
    for (int dd = 0; dd < 8; ++dd) {
      const int sj = vj0 ^ (dd << 3);         // (d&7)==dd for both d rows
      unsigned pk0 = (unsigned)vr[0][dd] | ((unsigned)vr[2][dd] << 16);
      unsigned pk1 = (unsigned)vr[1][dd] | ((unsigned)vr[3][dd] << 16);
      *(unsigned*)&lVb[(vd0 + dd) * 64 + sj] = pk0;
      *(unsigned*)&lVb[(vd0 + 8 + dd) * 64 + sj] = pk1;
    }
  };

  loadV(0);
  stageK(0, 0);
  writeV(0);
  __syncthreads();

  f32x4 acc_o[2][8];
#pragma unroll
  for (int mi = 0; mi < 2; ++mi)
#pragma unroll
    for (int i = 0; i < 8; ++i) acc_o[mi][i] = f32x4{0.f, 0.f, 0.f, 0.f};
  float mrun[2], lrun[2];
#pragma unroll
  for (int mi = 0; mi < 2; ++mi) { mrun[mi] = -__builtin_inff(); lrun[mi] = 0.f; }

  const float SL2E = 0.12751744f;
  const int qrow0 = qb * 128 + w * 32;

  for (int t = 0; t < nt; ++t) {
    const int kv0 = t * 64;
    const bool pre = (t + 1 < nt);
    if (pre) { loadV(t + 1); stageK(t + 1, (t + 1) & 1); }

    const bool active = (kv0 <= qrow0 + 31);
    if (active) {
      const unsigned short* lKc = &lK[t & 1][0];
      const unsigned short* lVc = &lV[t & 1][0];
      f32x4 sacc[4][2];
#pragma unroll
      for (int jb = 0; jb < 4; ++jb) {
        sacc[jb][0] = f32x4{0.f, 0.f, 0.f, 0.f};
        sacc[jb][1] = f32x4{0.f, 0.f, 0.f, 0.f};
      }
      __builtin_amdgcn_s_setprio(1);
#pragma unroll
      for (int jb = 0; jb < 4; ++jb) {
        const int r = jb * 16 + l15;
#pragma unroll
        for (int ks = 0; ks < 4; ++ks) {
          const int s = ks * 4 + g;
          bf16x8 kf = *(const bf16x8*)&lKc[r * 128 + (s ^ (r & 7)) * 8];
          sacc[jb][0] = MFMA16(kf, qf[0][ks], sacc[jb][0]);
          sacc[jb][1] = MFMA16(kf, qf[1][ks], sacc[jb][1]);
        }
      }
      __builtin_amdgcn_s_setprio(0);

      const bool need_mask = (kv0 + 63 >= qrow0);
      float psc_l[2];
      bool defer_mi[2];
#pragma unroll
      for (int mi = 0; mi < 2; ++mi) {
        const int icol = qrow0 + mi * 16 + l15;
        f32x4 pe[4];
#pragma unroll
        for (int jb = 0; jb < 4; ++jb) {
#pragma unroll
          for (int rr = 0; rr < 4; ++rr) {
            float tv = sacc[jb][mi][rr] * SL2E;
            if (need_mask && (kv0 + jb * 16 + g * 4 + rr > icol))
              tv = -__builtin_inff();
            pe[jb][rr] = tv;
          }
        }
        f32x4 m4 = f32x4{fmaxf(fmaxf(pe[0][0], pe[1][0]), fmaxf(pe[2][0], pe[3][0])),
                         fmaxf(fmaxf(pe[0][1], pe[1][1]), fmaxf(pe[2][1], pe[3][1])),
                         fmaxf(fmaxf(pe[0][2], pe[1][2]), fmaxf(pe[2][2], pe[3][2])),
                         fmaxf(fmaxf(pe[0][3], pe[1][3]), fmaxf(pe[2][3], pe[3][3]))};
        float mx = fmaxf(fmaxf(m4[0], m4[1]), fmaxf(m4[2], m4[3]));
        mx = fmaxf(mx, __shfl_xor(mx, 16));
        mx = fmaxf(mx, __shfl_xor(mx, 32));
        // T13: defer the max update when growth <= 8 (wave-uniform)
        const bool dfr = (__all(mx - mrun[mi] <= 8.0f) != 0);
        defer_mi[mi] = dfr;
        if (dfr) {
          psc_l[mi] = 1.0f;
        } else {
          const float mnew = fmaxf(mrun[mi], mx);
          psc_l[mi] = exp2f(mrun[mi] - mnew);
          mrun[mi] = mnew;
        }
        float rs = 0.f;
#pragma unroll
        for (int jb = 0; jb < 4; ++jb) {
#pragma unroll
          for (int rr = 0; rr < 4; ++rr) {
            const float e = exp2f(pe[jb][rr] - mrun[mi]);  // <= 2^8 if deferred
            pe[jb][rr] = e;
            rs += e;
          }
        }
        rs += __shfl_xor(rs, 16);
        rs += __shfl_xor(rs, 32);
        lrun[mi] = lrun[mi] * psc_l[mi] + rs;
        // ---- P -> per-wave LDS: b64 packed, swizzled stride-64
#pragma unroll
        for (int jb = 0; jb < 4; ++jb) {
          u32x2 pw;
          pw[0] = packbf2(pe[jb][0], pe[jb][1]);
          pw[1] = packbf2(pe[jb][2], pe[jb][3]);
          *(u32x2*)&lP[w][(mi * 16 + l15) * 64 +
                          ((jb * 16 + g * 4) ^ ((l15 & 7) << 3))] = pw;
        }
      }
      // fence: forbid hoisting the pa ds_reads above the lP ds_writes
      __builtin_amdgcn_sched_barrier(0);

      // rescale acc_o only when not deferred (wave-uniform branch per mi)
#pragma unroll
      for (int mi = 0; mi < 2; ++mi) {
        if (!defer_mi[mi]) {
          float psc_pv[4];
#pragma unroll
          for (int r = 0; r < 4; ++r)
            psc_pv[r] = __shfl(psc_l[mi], g * 4 + r);
#pragma unroll
          for (int nb = 0; nb < 8; ++nb)
#pragma unroll
            for (int r = 0; r < 4; ++r) acc_o[mi][nb][r] *= psc_pv[r];
        }
      }

      bf16x8 pa[2][2];
#pragma unroll
      for (int mi = 0; mi < 2; ++mi)
#pragma unroll
        for (int h = 0; h < 2; ++h)
          pa[mi][h] = *(const bf16x8*)&lP[w][(mi * 16 + l15) * 64 +
                                            ((h * 32 + g * 8) ^ ((l15 & 7) << 3))];
      __builtin_amdgcn_s_setprio(1);
#pragma unroll
      for (int nb = 0; nb < 8; ++nb) {
        const int vrow = nb * 16 + l15;
#pragma unroll
        for (int h = 0; h < 2; ++h) {
          bf16x8 vf = *(const bf16x8*)&lVc[vrow * 64 +
                                           ((h * 32 + g * 8) ^ ((vrow & 7) << 3))];
          acc_o[0][nb] = MFMA16(pa[0][h], vf, acc_o[0][nb]);
          acc_o[1][nb] = MFMA16(pa[1][h], vf, acc_o[1][nb]);
        }
      }
      __builtin_amdgcn_s_setprio(0);
    }

    if (pre) writeV((t + 1) & 1);   // other parity: last read at iter t-1
    __syncthreads();                // publish lK[(t+1)&1] (vmcnt drain) + lV
  }

  const int b = bh >> 4, hh = bh & 15;
  float linv[2][4];
#pragma unroll
  for (int mi = 0; mi < 2; ++mi)
#pragma unroll
    for (int r = 0; r < 4; ++r)
      linv[mi][r] = 1.0f / __shfl(lrun[mi], g * 4 + r);
#pragma unroll
  for (int mi = 0; mi < 2; ++mi)
#pragma unroll
    for (int nb = 0; nb < 8; ++nb)
#pragma unroll
      for (int r = 0; r < 4; ++r) {
        const int i = qb * 128 + w * 32 + mi * 16 + g * 4 + r;
        const float o = acc_o[mi][nb][r] * linv[mi][r];
        O[((size_t)(b * 2048 + i)) * 2048 + hh * 128 + nb * 16 + l15] = f2bf(o);
      }
}

// ---------- launch ----------
extern "C" void kernel_launch(void* const* d_in, const int* in_sizes, int n_in,
                              void* d_out, int out_size, void* d_ws, size_t ws_size,
                              hipStream_t stream) {
  const float* x  = (const float*)d_in[0];
  const float* wq = (const float*)d_in[1];
  const float* bq = (const float*)d_in[2];
  const float* wk = (const float*)d_in[3];
  const float* bk = (const float*)d_in[4];
  const float* wv = (const float*)d_in[5];
  const float* bv = (const float*)d_in[6];
  const float* wo = (const float*)d_in[7];
  const float* bo = (const float*)d_in[8];

  const size_t NX = (size_t)2 * 2048 * 2048;
  const size_t NW = (size_t)2048 * 2048;
  const size_t need = (NX + 4 * NW + 3 * NX) * sizeof(unsigned short);  // 96 MB
  if (ws_size < need) return;
  unsigned short* xbf  = (unsigned short*)d_ws;
  unsigned short* wqb  = xbf + NX;
  unsigned short* wkb  = wqb + NW;
  unsigned short* wvb  = wkb + NW;
  unsigned short* wob  = wvb + NW;
  unsigned short* qbuf = wob + NW;
  unsigned short* kbuf = qbuf + NX;
  unsigned short* vbuf = kbuf + NX;
  unsigned short* aobuf = xbf;  // x dead after gemm_qkv (stream-ordered)

  cvt_all<<<dim3(4096, 6), 256, 0, stream>>>(x, wq, wk, wv, wo,
                                             xbf, wqb, wkb, wvb, wob);
  gemm_qkv<<<dim3(16, 16, 3), 512, 0, stream>>>(xbf, wqb, bq, wkb, bk, wvb, bv,
                                                qbuf, kbuf, vbuf);
  attn_fwd<<<dim3(16, 32), 256, 0, stream>>>(qbuf, kbuf, vbuf, aobuf);
  gemm_out<<<dim3(16, 16), 512, 0, stream>>>(aobuf, wob, bo, (float*)d_out);
}